// Round 2
// baseline (231.782 us; speedup 1.0000x reference)
//
#include <hip/hip_runtime.h>
#include <hip/hip_fp16.h>
#include <math.h>

#define NFEAT 128
#define NCLS  64
#define RQ8   8             // uint4 per fp16 64-wide row (128 B)
#define WSTR  132           // W LDS row stride in halves
#define NBLK  256           // grid for edge-stream passes

// ---------- helpers ----------

typedef _Float16 h2v __attribute__((ext_vector_type(2)));

__device__ __forceinline__ float dot2acc(unsigned int hv, unsigned int wv, float c) {
#if __has_builtin(__builtin_amdgcn_fdot2)
    union { unsigned int u; h2v v; } a, bq; a.u = hv; bq.u = wv;
    return __builtin_amdgcn_fdot2(a.v, bq.v, c, false);
#else
    union { unsigned int u; __half2 h; } a, bq; a.u = hv; bq.u = wv;
    float2 fa = __half22float2(a.h), fb = __half22float2(bq.h);
    return fmaf(fa.x, fb.x, fmaf(fa.y, fb.y, c));
#endif
}

// packed fp16 accumulate: 4 v_pk_add_f16 per 16B row-chunk
__device__ __forceinline__ void acc4(__half2 a[4], uint4 v) {
    union { uint4 u; __half2 h[4]; } c; c.u = v;
    a[0] = __hadd2(a[0], c.h[0]); a[1] = __hadd2(a[1], c.h[1]);
    a[2] = __hadd2(a[2], c.h[2]); a[3] = __hadd2(a[3], c.h[3]);
}

__device__ __forceinline__ __half2 red8(__half2 a) {   // reduce across 8 sub-slots
    union { __half2 h; int i; } u, v;
    u.h = a; v.i = __shfl_xor(u.i, 8);  a = __hadd2(a, v.h);
    u.h = a; v.i = __shfl_xor(u.i, 16); a = __hadd2(a, v.h);
    u.h = a; v.i = __shfl_xor(u.i, 32); a = __hadd2(a, v.h);
    return a;
}

// ---------- build pass 0: zero the degree array ----------
__global__ __launch_bounds__(256) void zero_kernel(int4* __restrict__ p, int n4) {
    int i = blockIdx.x * 256 + threadIdx.x;
    if (i < n4) p[i] = int4{0, 0, 0, 0};
}

// ---------- build pass 1: per-node in-degree via global atomics (L2-resident) ----------
__global__ __launch_bounds__(256) void deg_kernel(const int* __restrict__ dst,
                                                  int* __restrict__ deg,
                                                  int E4, int E) {
    for (int idx = blockIdx.x * 256 + threadIdx.x; idx < E4; idx += NBLK * 256) {
        int base = idx * 4;
        if (base + 3 < E) {
            int4 d = ((const int4*)dst)[idx];
            atomicAdd(&deg[d.x], 1); atomicAdd(&deg[d.y], 1);
            atomicAdd(&deg[d.z], 1); atomicAdd(&deg[d.w], 1);
        } else {
            for (int e = base; e < E; ++e) atomicAdd(&deg[dst[e]], 1);
        }
    }
}

// ---------- build pass 2a: per-256-node-block total of padded row lengths ----------
// row length = deg + 1 (self-loop) padded to x8
__global__ __launch_bounds__(256) void rowsum_kernel(const int* __restrict__ deg,
                                                     int* __restrict__ btot, int N) {
    __shared__ int lds[256];
    const int tid = threadIdx.x;
    int i = blockIdx.x * 256 + tid;
    int cp = (i < N) ? ((deg[i] + 8) & ~7) : 0;
    lds[tid] = cp;
    __syncthreads();
    for (int off = 128; off > 0; off >>= 1) {
        if (tid < off) lds[tid] += lds[tid + off];
        __syncthreads();
    }
    if (tid == 0) btot[blockIdx.x] = lds[0];
}

// ---------- build pass 2b: per-node row offsets + cursors + dinv + self/pad entries ----------
// Each block locally sums btot[0..B) (tiny), then scans its 256 padded lengths.
__global__ __launch_bounds__(256) void rowscan_kernel(const int* __restrict__ deg,
                                                      const int* __restrict__ btot,
                                                      int* __restrict__ rbeg,
                                                      int* __restrict__ rend,
                                                      int* __restrict__ cur,
                                                      float* __restrict__ dinv,
                                                      int* __restrict__ csr, int N) {
    __shared__ int lds[256];
    __shared__ int base_s;
    const int tid = threadIdx.x;
    const int B = blockIdx.x;

    lds[tid] = (tid < B) ? btot[tid] : 0;          // B < nb <= 256
    __syncthreads();
    for (int off = 128; off > 0; off >>= 1) {
        if (tid < off) lds[tid] += lds[tid + off];
        __syncthreads();
    }
    if (tid == 0) base_s = lds[0];
    __syncthreads();
    const int base = base_s;

    int i = B * 256 + tid;
    int d  = (i < N) ? deg[i] : 0;
    int cp = (i < N) ? ((d + 8) & ~7) : 0;
    lds[tid] = cp;
    __syncthreads();
    for (int off = 1; off < 256; off <<= 1) {      // inclusive scan
        int t = (tid >= off) ? lds[tid - off] : 0;
        __syncthreads();
        lds[tid] += t;
        __syncthreads();
    }
    if (i < N) {
        int start = base + lds[tid] - cp;
        rbeg[i] = start;
        rend[i] = start + cp;
        cur[i]  = start;                           // scatter fills [start, start+d)
        dinv[i] = rsqrtf((float)d + 1.0f);         // +1 self-loop
        csr[start + d] = i;                        // self entry baked into row
        for (int p = start + d + 1; p < start + cp; ++p) csr[p] = N;   // pads -> dummy row
    }
}

// ---------- build pass 3: scatter src into csr via per-node atomic cursors ----------
__global__ __launch_bounds__(256) void scatter_csr_kernel(const int* __restrict__ src,
                                                          const int* __restrict__ dst,
                                                          int* __restrict__ cur,
                                                          int* __restrict__ csr,
                                                          int E4, int E) {
    for (int idx = blockIdx.x * 256 + threadIdx.x; idx < E4; idx += NBLK * 256) {
        int base = idx * 4;
        if (base + 3 < E) {
            int4 s = ((const int4*)src)[idx];
            int4 d = ((const int4*)dst)[idx];
            int p;
            p = atomicAdd(&cur[d.x], 1); csr[p] = s.x;
            p = atomicAdd(&cur[d.y], 1); csr[p] = s.y;
            p = atomicAdd(&cur[d.z], 1); csr[p] = s.z;
            p = atomicAdd(&cur[d.w], 1); csr[p] = s.w;
        } else {
            for (int e = base; e < E; ++e) {
                int p = atomicAdd(&cur[dst[e]], 1);
                csr[p] = src[e];
            }
        }
    }
}

// ---------- projection first (SGC linearity): zh = fp16(dinv_i * (x_i @ W^T)) ----------
__global__ __launch_bounds__(512) void gemm_kernel(const float* __restrict__ x,
                                                   const float* __restrict__ W,
                                                   const float* __restrict__ dinv,
                                                   __half* __restrict__ zh,
                                                   __half* __restrict__ y1h, int N) {
    __shared__ __half Wl[NCLS * WSTR];
    __shared__ __align__(16) __half HT[64][NFEAT];

    const int tid = threadIdx.x;
    const int w = tid >> 6, lane = tid & 63;

    if (blockIdx.x == 0 && tid < 32) {             // zero dummy rows (row N, 16 uint2 each)
        if (tid < 16) ((uint2*)zh)[(size_t)N * 16 + tid] = uint2{0u, 0u};
        else          ((uint2*)y1h)[(size_t)N * 16 + (tid - 16)] = uint2{0u, 0u};
    }

    for (int e = tid; e < NCLS * NFEAT; e += 512) {
        int r = e >> 7, c = e & 127;
        Wl[r * WSTR + c] = __float2half(W[e]);
    }
    {
        const float4* srcf = (const float4*)(x + (size_t)blockIdx.x * 64 * NFEAT);
        uint2* dh = (uint2*)&HT[0][0];
        const int row0 = blockIdx.x * 64;
        #pragma unroll
        for (int t = 0; t < 4; ++t) {
            int e = tid + 512 * t;                 // float4 index, 2048 total (32 per row)
            float4 f = (row0 + (e >> 5) < N) ? srcf[e] : float4{0.f, 0.f, 0.f, 0.f};
            union { uint2 u; __half2 h[2]; } r;
            r.h[0] = __floats2half2_rn(f.x, f.y);
            r.h[1] = __floats2half2_rn(f.z, f.w);
            dh[e] = r.u;
        }
    }
    __syncthreads();

    unsigned int wreg[64];
    {
        const uint2* wr = (const uint2*)&Wl[lane * WSTR];
        #pragma unroll
        for (int t = 0; t < 32; ++t) {
            uint2 v = wr[t];
            wreg[2 * t] = v.x; wreg[2 * t + 1] = v.y;
        }
    }

    #pragma unroll 1
    for (int r = 0; r < 8; ++r) {
        int node = blockIdx.x * 64 + w * 8 + r;
        if (node >= N) break;
        const unsigned int* hrow = (const unsigned int*)&HT[w * 8 + r][0];
        float dot = 0.f;
        #pragma unroll
        for (int t = 0; t < 64; ++t)
            dot = dot2acc(hrow[t], wreg[t], dot);
        zh[(size_t)node * NCLS + lane] = __float2half(dinv[node] * dot);
    }
}

// ---------- gather core: 64-wide rows, 8 subs x 8 q, 32-edge main loop ----------
__device__ __forceinline__ void gather_row64(__half2 a[4], const uint4* __restrict__ X,
                                             const int* __restrict__ csr,
                                             int ks, int ke, int sub, int q, int Nd) {
    int k = ks;
    int j0, j1, j2, j3;
    bool have = (k + 32 <= ke);
    if (have) {
        j0 = csr[k + sub];      j1 = csr[k + 8 + sub];
        j2 = csr[k + 16 + sub]; j3 = csr[k + 24 + sub];
    }
    while (have) {
        uint4 v0 = X[(size_t)j0 * RQ8 + q];
        uint4 v1 = X[(size_t)j1 * RQ8 + q];
        uint4 v2 = X[(size_t)j2 * RQ8 + q];
        uint4 v3 = X[(size_t)j3 * RQ8 + q];
        k += 32;
        have = (k + 32 <= ke);
        if (have) {                               // prefetch next indices
            j0 = csr[k + sub];      j1 = csr[k + 8 + sub];
            j2 = csr[k + 16 + sub]; j3 = csr[k + 24 + sub];
        }
        acc4(a, v0); acc4(a, v1); acc4(a, v2); acc4(a, v3);
    }
    int rem = (ke - k) >> 3;                      // 0..3 rounds of 8, wave-uniform
    if (rem) {
        int t0 = csr[k + sub];
        int t1 = csr[k + 8 + sub];      // overrun reads land in end-of-csr slack
        int t2 = csr[k + 16 + sub];     // values discarded via redirect below
        if (rem < 2) t1 = Nd;
        if (rem < 3) t2 = Nd;
        uint4 v0 = X[(size_t)t0 * RQ8 + q];
        uint4 v1 = X[(size_t)t1 * RQ8 + q];
        uint4 v2 = X[(size_t)t2 * RQ8 + q];
        acc4(a, v0); acc4(a, v1); acc4(a, v2);
    }
}

// ---------- hop1: out[i] = fp16( dinv_i^s * sum_{j in row(i)} in[j] ), 64-wide ----------
// (self term is baked into the csr row)
template <int SQUARE>
__global__ __launch_bounds__(256) void hop64_kernel(const __half* __restrict__ in_h,
                                                    const float* __restrict__ dinv,
                                                    const int* __restrict__ rbeg,
                                                    const int* __restrict__ rend,
                                                    const int* __restrict__ csr,
                                                    __half* __restrict__ out_h, int N) {
    const int tid = threadIdx.x;
    const int w = tid >> 6, lane = tid & 63;
    const int i = blockIdx.x * 4 + w;
    if (i >= N) return;                           // wave-uniform; no barriers
    const int sub = lane >> 3;
    const int q = lane & 7;
    const uint4* X = (const uint4*)in_h;

    __half2 a[4];
    a[0] = __float2half2_rn(0.f); a[1] = a[0]; a[2] = a[0]; a[3] = a[0];

    int ks = rbeg[i], ke = rend[i];
    gather_row64(a, X, csr, ks, ke, sub, q, N);

    a[0] = red8(a[0]); a[1] = red8(a[1]); a[2] = red8(a[2]); a[3] = red8(a[3]);

    if (sub == 0) {
        float di = dinv[i];
        float s = SQUARE ? di * di : di;
        union { uint4 u; __half2 h[4]; } r;
        #pragma unroll
        for (int t = 0; t < 4; ++t) {
            float2 f = __half22float2(a[t]);
            r.h[t] = __floats2half2_rn(s * f.x, s * f.y);
        }
        ((uint4*)out_h)[(size_t)i * RQ8 + q] = r.u;
    }
}

// ---------- hop2 fused with bias + log_softmax: out fp32 [N,64] ----------
__global__ __launch_bounds__(256) void hop2cls_kernel(const __half* __restrict__ in_h,
                                                      const float* __restrict__ dinv,
                                                      const int* __restrict__ rbeg,
                                                      const int* __restrict__ rend,
                                                      const int* __restrict__ csr,
                                                      const float* __restrict__ b,
                                                      float* __restrict__ out, int N) {
    const int tid = threadIdx.x;
    const int w = tid >> 6, lane = tid & 63;
    const int i = blockIdx.x * 4 + w;
    if (i >= N) return;
    const int sub = lane >> 3;
    const int q = lane & 7;
    const uint4* X = (const uint4*)in_h;

    float4 b0 = ((const float4*)b)[q * 2];
    float4 b1 = ((const float4*)b)[q * 2 + 1];

    __half2 a[4];
    a[0] = __float2half2_rn(0.f); a[1] = a[0]; a[2] = a[0]; a[3] = a[0];

    int ks = rbeg[i], ke = rend[i];
    gather_row64(a, X, csr, ks, ke, sub, q, N);

    a[0] = red8(a[0]); a[1] = red8(a[1]); a[2] = red8(a[2]); a[3] = red8(a[3]);

    if (sub == 0) {                                  // lanes 0..7 hold the 64-class row
        float di = dinv[i];
        float f[8];
        float2 p;
        p = __half22float2(a[0]); f[0] = fmaf(di, p.x, b0.x); f[1] = fmaf(di, p.y, b0.y);
        p = __half22float2(a[1]); f[2] = fmaf(di, p.x, b0.z); f[3] = fmaf(di, p.y, b0.w);
        p = __half22float2(a[2]); f[4] = fmaf(di, p.x, b1.x); f[5] = fmaf(di, p.y, b1.y);
        p = __half22float2(a[3]); f[6] = fmaf(di, p.x, b1.z); f[7] = fmaf(di, p.y, b1.w);
        float m = f[0];
        #pragma unroll
        for (int t = 1; t < 8; ++t) m = fmaxf(m, f[t]);
        m = fmaxf(m, __shfl_xor(m, 1));              // partners stay within lanes 0..7
        m = fmaxf(m, __shfl_xor(m, 2));
        m = fmaxf(m, __shfl_xor(m, 4));
        float se = 0.f;
        #pragma unroll
        for (int t = 0; t < 8; ++t) se += __expf(f[t] - m);
        se += __shfl_xor(se, 1);
        se += __shfl_xor(se, 2);
        se += __shfl_xor(se, 4);
        float ls = m + logf(se);
        float4 o0 = {f[0] - ls, f[1] - ls, f[2] - ls, f[3] - ls};
        float4 o1 = {f[4] - ls, f[5] - ls, f[6] - ls, f[7] - ls};
        float4* op = (float4*)(out + (size_t)i * NCLS);
        op[q * 2] = o0; op[q * 2 + 1] = o1;
    }
}

// ---------- launch ----------

static inline size_t align256(size_t v) { return (v + 255) & ~(size_t)255; }

extern "C" void kernel_launch(void* const* d_in, const int* in_sizes, int n_in,
                              void* d_out, int out_size, void* d_ws, size_t ws_size,
                              hipStream_t stream) {
    const float* x  = (const float*)d_in[0];
    const int*   ei = (const int*)d_in[1];
    const float* W  = (const float*)d_in[2];
    const float* b  = (const float*)d_in[3];
    float* out = (float*)d_out;

    const int N = in_sizes[0] / NFEAT;   // 50000
    const int E = in_sizes[1] / 2;       // 800000
    const int* src = ei;
    const int* dst = ei + E;
    const int NB = (N + 255) >> 8;       // 196 blocks of 256 nodes

    // csr capacity: sum of padded row lens <= E + 8*N, plus 64-int overrun slack
    const int CSR_CAP = E + 8 * N + 64;

    char* ws = (char*)d_ws;
    size_t o = 0;
    int*    deg   = (int*)(ws + o);    o += align256((size_t)((N + 3) & ~3) * 4);
    int*    btot  = (int*)(ws + o);    o += align256(256 * 4);
    int*    rbeg  = (int*)(ws + o);    o += align256((size_t)N * 4);
    int*    rend  = (int*)(ws + o);    o += align256((size_t)N * 4);
    int*    cur   = (int*)(ws + o);    o += align256((size_t)N * 4);
    float*  dinv  = (float*)(ws + o);  o += align256((size_t)N * 4);
    int*    csr   = (int*)(ws + o);    o += align256((size_t)CSR_CAP * 4);
    __half* zh    = (__half*)(ws + o); o += align256((size_t)(N + 1) * NCLS * 2);
    __half* y1h   = (__half*)(ws + o); o += align256((size_t)(N + 1) * NCLS * 2);

    const int E4 = (E + 3) / 4;
    const int n4 = (N + 3) / 4;

    zero_kernel<<<(n4 + 255) / 256, 256, 0, stream>>>((int4*)deg, n4);
    deg_kernel<<<NBLK, 256, 0, stream>>>(dst, deg, E4, E);
    rowsum_kernel<<<NB, 256, 0, stream>>>(deg, btot, N);
    rowscan_kernel<<<NB, 256, 0, stream>>>(deg, btot, rbeg, rend, cur, dinv, csr, N);
    scatter_csr_kernel<<<NBLK, 256, 0, stream>>>(src, dst, cur, csr, E4, E);
    gemm_kernel<<<(N + 63) / 64, 512, 0, stream>>>(x, W, dinv, zh, y1h, N);
    hop64_kernel<1><<<(N + 3) / 4, 256, 0, stream>>>(zh, dinv, rbeg, rend, csr, y1h, N);
    hop2cls_kernel<<<(N + 3) / 4, 256, 0, stream>>>(y1h, dinv, rbeg, rend, csr, b, out, N);
}

// Round 3
// 155.844 us; speedup vs baseline: 1.4873x; 1.4873x over previous
//
#include <hip/hip_runtime.h>
#include <hip/hip_fp16.h>
#include <math.h>

#define NFEAT 128
#define NCLS  64
#define RQ8   8             // uint4 per fp16 64-wide row (128 B)
#define WSTR  132           // W LDS row stride in halves
#define NBLK  256           // grid for edge-stream passes
#define BSLACK 2048         // per-bucket csr slack: 256 rows x (self + <=7 pads)

// ---------- helpers ----------

typedef _Float16 h2v __attribute__((ext_vector_type(2)));

__device__ __forceinline__ float dot2acc(unsigned int hv, unsigned int wv, float c) {
#if __has_builtin(__builtin_amdgcn_fdot2)
    union { unsigned int u; h2v v; } a, bq; a.u = hv; bq.u = wv;
    return __builtin_amdgcn_fdot2(a.v, bq.v, c, false);
#else
    union { unsigned int u; __half2 h; } a, bq; a.u = hv; bq.u = wv;
    float2 fa = __half22float2(a.h), fb = __half22float2(bq.h);
    return fmaf(fa.x, fb.x, fmaf(fa.y, fb.y, c));
#endif
}

// packed fp16 accumulate: 4 v_pk_add_f16 per 16B row-chunk
__device__ __forceinline__ void acc4(__half2 a[4], uint4 v) {
    union { uint4 u; __half2 h[4]; } c; c.u = v;
    a[0] = __hadd2(a[0], c.h[0]); a[1] = __hadd2(a[1], c.h[1]);
    a[2] = __hadd2(a[2], c.h[2]); a[3] = __hadd2(a[3], c.h[3]);
}

__device__ __forceinline__ __half2 red8(__half2 a) {   // reduce across 8 sub-slots
    union { __half2 h; int i; } u, v;
    u.h = a; v.i = __shfl_xor(u.i, 8);  a = __hadd2(a, v.h);
    u.h = a; v.i = __shfl_xor(u.i, 16); a = __hadd2(a, v.h);
    u.h = a; v.i = __shfl_xor(u.i, 32); a = __hadd2(a, v.h);
    return a;
}

// block-wide (256 thr) exclusive scan via wave shfl; scratch >= 8 ints; 3 barriers
__device__ __forceinline__ int block_excl_scan_256(int v, int tid, int* scratch, int* total) {
    const int lane = tid & 63, wv = tid >> 6;
    __syncthreads();                               // protect scratch reuse
    int x = v;
    #pragma unroll
    for (int off = 1; off < 64; off <<= 1) {
        int y = __shfl_up(x, off);
        if (lane >= off) x += y;
    }
    if (lane == 63) scratch[wv] = x;
    __syncthreads();
    if (wv == 0 && lane < 4) {
        int t = scratch[lane];
        int y = __shfl_up(t, 1); if (lane >= 1) t += y;
        y = __shfl_up(t, 2);     if (lane >= 2) t += y;
        scratch[4 + lane] = t;                     // inclusive wave-prefix
    }
    __syncthreads();
    int wbase = (wv == 0) ? 0 : scratch[4 + wv - 1];
    if (total) *total = scratch[7];
    return wbase + x - v;                          // exclusive prefix of v
}

// ---------- build pass 1: 256-node-bucket histogram (LDS atomics) ----------
__global__ __launch_bounds__(256) void hist_kernel(const int* __restrict__ dst,
                                                   int* __restrict__ h,
                                                   int E4, int E, int nb) {
    __shared__ int lh[256];
    const int tid = threadIdx.x;
    lh[tid] = 0;
    __syncthreads();
    for (int idx = blockIdx.x * 256 + tid; idx < E4; idx += NBLK * 256) {
        int base = idx * 4;
        if (base + 3 < E) {
            int4 d = ((const int4*)dst)[idx];
            atomicAdd(&lh[d.x >> 8], 1); atomicAdd(&lh[d.y >> 8], 1);
            atomicAdd(&lh[d.z >> 8], 1); atomicAdd(&lh[d.w >> 8], 1);
        } else {
            for (int e = base; e < E; ++e) atomicAdd(&lh[dst[e] >> 8], 1);
        }
    }
    __syncthreads();
    if (tid < nb) h[blockIdx.x * nb + tid] = lh[tid];
}

// pass 2: per bucket, exclusive scan over its 256 block-counts + total
__global__ __launch_bounds__(256) void colscan_kernel(int* __restrict__ h,
                                                      int* __restrict__ btot, int nb) {
    __shared__ int scratch[8];
    const int tid = threadIdx.x;
    const int B = blockIdx.x;
    int v = h[tid * nb + B];
    int tot;
    int pre = block_excl_scan_256(v, tid, scratch, &tot);
    h[tid * nb + B] = pre;                         // exclusive within bucket
    if (tid == 0) btot[B] = tot;
}

// pass 3: replay edges, write packed (src<<8 | dst&255) into bucket-ordered COO.
// Bucket bases recomputed locally from btot (<=256 values).
__global__ __launch_bounds__(256) void bucket_scatter_kernel(const int* __restrict__ src,
                                                             const int* __restrict__ dst,
                                                             const int* __restrict__ h,
                                                             const int* __restrict__ btot,
                                                             unsigned int* __restrict__ bedg,
                                                             int E4, int E, int nb) {
    __shared__ int cur[256];
    __shared__ int scratch[8];
    const int tid = threadIdx.x;
    int bt = (tid < nb) ? btot[tid] : 0;
    int pre = block_excl_scan_256(bt, tid, scratch, nullptr);
    if (tid < nb) cur[tid] = pre + h[blockIdx.x * nb + tid];
    __syncthreads();
    for (int idx = blockIdx.x * 256 + tid; idx < E4; idx += NBLK * 256) {
        int base = idx * 4;
        if (base + 3 < E) {
            int4 s = ((const int4*)src)[idx];
            int4 d = ((const int4*)dst)[idx];
            int p;
            p = atomicAdd(&cur[d.x >> 8], 1); bedg[p] = ((unsigned)s.x << 8) | (d.x & 255);
            p = atomicAdd(&cur[d.y >> 8], 1); bedg[p] = ((unsigned)s.y << 8) | (d.y & 255);
            p = atomicAdd(&cur[d.z >> 8], 1); bedg[p] = ((unsigned)s.z << 8) | (d.z & 255);
            p = atomicAdd(&cur[d.w >> 8], 1); bedg[p] = ((unsigned)s.w << 8) | (d.w & 255);
        } else {
            for (int e = base; e < E; ++e) {
                int p = atomicAdd(&cur[dst[e] >> 8], 1);
                bedg[p] = ((unsigned)src[e] << 8) | (dst[e] & 255);
            }
        }
    }
}

// pass 4: per-bucket LDS counting sort -> csr rows (self baked in, padded x8, pads = N),
// rbeg/rend, dinv. Bucket edge range + csr base recomputed locally from btot.
__global__ __launch_bounds__(256) void drain_kernel(const unsigned int* __restrict__ bedg,
                                                    const int* __restrict__ btot,
                                                    int* __restrict__ csr,
                                                    int* __restrict__ rbeg,
                                                    int* __restrict__ rend,
                                                    float* __restrict__ dinv,
                                                    int N, int nb) {
    __shared__ int lcnt[256];
    __shared__ int loc[256];
    __shared__ int scratch[8];
    __shared__ int s0_s, s1_s;
    const int B = blockIdx.x;
    const int tid = threadIdx.x;

    int bt = (tid < nb) ? btot[tid] : 0;
    int pre = block_excl_scan_256(bt, tid, scratch, nullptr);
    if (tid == B) { s0_s = pre; s1_s = pre + bt; }
    lcnt[tid] = 0;
    __syncthreads();
    const int s0 = s0_s, s1 = s1_s;

    for (int e = s0 + tid; e < s1; e += 256)
        atomicAdd(&lcnt[bedg[e] & 255u], 1);
    __syncthreads();

    const int c = lcnt[tid];
    const int cp = (c + 8) & ~7;                   // +1 self, padded to x8
    int rpre = block_excl_scan_256(cp, tid, scratch, nullptr);
    const int base = s0 + BSLACK * B;              // csr region for this bucket
    loc[tid] = base + rpre;                        // row start
    __syncthreads();
    lcnt[tid] = loc[tid];                          // reuse as cursor
    __syncthreads();

    for (int e = s0 + tid; e < s1; e += 256) {
        unsigned int Ev = bedg[e];
        int p = atomicAdd(&lcnt[Ev & 255u], 1);
        csr[p] = (int)(Ev >> 8);
    }
    __syncthreads();

    int i = B * 256 + tid;
    if (i < N) {
        int start = loc[tid], end = start + cp;
        int q = lcnt[tid];                         // == start + c
        csr[q++] = i;                              // self entry baked into row
        for (int p = q; p < end; ++p) csr[p] = N;  // <=7 pads (dummy row)
        rbeg[i] = start; rend[i] = end;
        dinv[i] = rsqrtf((float)c + 1.0f);         // +1 self-loop
    }
}

// ---------- projection first (SGC linearity): zh = fp16(dinv_i * (x_i @ W^T)) ----------
__global__ __launch_bounds__(512) void gemm_kernel(const float* __restrict__ x,
                                                   const float* __restrict__ W,
                                                   const float* __restrict__ dinv,
                                                   __half* __restrict__ zh,
                                                   __half* __restrict__ y1h, int N) {
    __shared__ __half Wl[NCLS * WSTR];
    __shared__ __align__(16) __half HT[64][NFEAT];

    const int tid = threadIdx.x;
    const int w = tid >> 6, lane = tid & 63;

    if (blockIdx.x == 0 && tid < 32) {             // zero dummy rows (row N, 16 uint2 each)
        if (tid < 16) ((uint2*)zh)[(size_t)N * 16 + tid] = uint2{0u, 0u};
        else          ((uint2*)y1h)[(size_t)N * 16 + (tid - 16)] = uint2{0u, 0u};
    }

    for (int e = tid; e < NCLS * NFEAT; e += 512) {
        int r = e >> 7, c = e & 127;
        Wl[r * WSTR + c] = __float2half(W[e]);
    }
    {
        const float4* srcf = (const float4*)(x + (size_t)blockIdx.x * 64 * NFEAT);
        uint2* dh = (uint2*)&HT[0][0];
        const int row0 = blockIdx.x * 64;
        #pragma unroll
        for (int t = 0; t < 4; ++t) {
            int e = tid + 512 * t;                 // float4 index, 2048 total (32 per row)
            float4 f = (row0 + (e >> 5) < N) ? srcf[e] : float4{0.f, 0.f, 0.f, 0.f};
            union { uint2 u; __half2 h[2]; } r;
            r.h[0] = __floats2half2_rn(f.x, f.y);
            r.h[1] = __floats2half2_rn(f.z, f.w);
            dh[e] = r.u;
        }
    }
    __syncthreads();

    unsigned int wreg[64];
    {
        const uint2* wr = (const uint2*)&Wl[lane * WSTR];
        #pragma unroll
        for (int t = 0; t < 32; ++t) {
            uint2 v = wr[t];
            wreg[2 * t] = v.x; wreg[2 * t + 1] = v.y;
        }
    }

    #pragma unroll 1
    for (int r = 0; r < 8; ++r) {
        int node = blockIdx.x * 64 + w * 8 + r;
        if (node >= N) break;
        const unsigned int* hrow = (const unsigned int*)&HT[w * 8 + r][0];
        float dot = 0.f;
        #pragma unroll
        for (int t = 0; t < 64; ++t)
            dot = dot2acc(hrow[t], wreg[t], dot);
        zh[(size_t)node * NCLS + lane] = __float2half(dinv[node] * dot);
    }
}

// ---------- gather core: 64-wide rows, 8 subs x 8 q, 32-edge main loop ----------
__device__ __forceinline__ void gather_row64(__half2 a[4], const uint4* __restrict__ X,
                                             const int* __restrict__ csr,
                                             int ks, int ke, int sub, int q, int Nd) {
    int k = ks;
    int j0, j1, j2, j3;
    bool have = (k + 32 <= ke);
    if (have) {
        j0 = csr[k + sub];      j1 = csr[k + 8 + sub];
        j2 = csr[k + 16 + sub]; j3 = csr[k + 24 + sub];
    }
    while (have) {
        uint4 v0 = X[(size_t)j0 * RQ8 + q];
        uint4 v1 = X[(size_t)j1 * RQ8 + q];
        uint4 v2 = X[(size_t)j2 * RQ8 + q];
        uint4 v3 = X[(size_t)j3 * RQ8 + q];
        k += 32;
        have = (k + 32 <= ke);
        if (have) {                               // prefetch next indices
            j0 = csr[k + sub];      j1 = csr[k + 8 + sub];
            j2 = csr[k + 16 + sub]; j3 = csr[k + 24 + sub];
        }
        acc4(a, v0); acc4(a, v1); acc4(a, v2); acc4(a, v3);
    }
    int rem = (ke - k) >> 3;                      // 0..3 rounds of 8, wave-uniform
    if (rem) {
        int t0 = csr[k + sub];
        int t1 = csr[k + 8 + sub];      // overrun reads land in bucket slack (garbage)
        int t2 = csr[k + 16 + sub];     // values discarded via redirect below
        if (rem < 2) t1 = Nd;
        if (rem < 3) t2 = Nd;
        uint4 v0 = X[(size_t)t0 * RQ8 + q];
        uint4 v1 = X[(size_t)t1 * RQ8 + q];
        uint4 v2 = X[(size_t)t2 * RQ8 + q];
        acc4(a, v0); acc4(a, v1); acc4(a, v2);
    }
}

// ---------- hop1: out[i] = fp16( dinv_i^s * sum_{j in row(i)} in[j] ), 64-wide ----------
// (self term baked into csr row)
template <int SQUARE>
__global__ __launch_bounds__(256) void hop64_kernel(const __half* __restrict__ in_h,
                                                    const float* __restrict__ dinv,
                                                    const int* __restrict__ rbeg,
                                                    const int* __restrict__ rend,
                                                    const int* __restrict__ csr,
                                                    __half* __restrict__ out_h, int N) {
    const int tid = threadIdx.x;
    const int w = tid >> 6, lane = tid & 63;
    const int i = blockIdx.x * 4 + w;
    if (i >= N) return;                           // wave-uniform; no barriers
    const int sub = lane >> 3;
    const int q = lane & 7;
    const uint4* X = (const uint4*)in_h;

    __half2 a[4];
    a[0] = __float2half2_rn(0.f); a[1] = a[0]; a[2] = a[0]; a[3] = a[0];

    int ks = rbeg[i], ke = rend[i];
    gather_row64(a, X, csr, ks, ke, sub, q, N);

    a[0] = red8(a[0]); a[1] = red8(a[1]); a[2] = red8(a[2]); a[3] = red8(a[3]);

    if (sub == 0) {
        float di = dinv[i];
        float s = SQUARE ? di * di : di;
        union { uint4 u; __half2 h[4]; } r;
        #pragma unroll
        for (int t = 0; t < 4; ++t) {
            float2 f = __half22float2(a[t]);
            r.h[t] = __floats2half2_rn(s * f.x, s * f.y);
        }
        ((uint4*)out_h)[(size_t)i * RQ8 + q] = r.u;
    }
}

// ---------- hop2 fused with bias + log_softmax: out fp32 [N,64] ----------
__global__ __launch_bounds__(256) void hop2cls_kernel(const __half* __restrict__ in_h,
                                                      const float* __restrict__ dinv,
                                                      const int* __restrict__ rbeg,
                                                      const int* __restrict__ rend,
                                                      const int* __restrict__ csr,
                                                      const float* __restrict__ b,
                                                      float* __restrict__ out, int N) {
    const int tid = threadIdx.x;
    const int w = tid >> 6, lane = tid & 63;
    const int i = blockIdx.x * 4 + w;
    if (i >= N) return;
    const int sub = lane >> 3;
    const int q = lane & 7;
    const uint4* X = (const uint4*)in_h;

    float4 b0 = ((const float4*)b)[q * 2];
    float4 b1 = ((const float4*)b)[q * 2 + 1];

    __half2 a[4];
    a[0] = __float2half2_rn(0.f); a[1] = a[0]; a[2] = a[0]; a[3] = a[0];

    int ks = rbeg[i], ke = rend[i];
    gather_row64(a, X, csr, ks, ke, sub, q, N);

    a[0] = red8(a[0]); a[1] = red8(a[1]); a[2] = red8(a[2]); a[3] = red8(a[3]);

    if (sub == 0) {                                  // lanes 0..7 hold the 64-class row
        float di = dinv[i];
        float f[8];
        float2 p;
        p = __half22float2(a[0]); f[0] = fmaf(di, p.x, b0.x); f[1] = fmaf(di, p.y, b0.y);
        p = __half22float2(a[1]); f[2] = fmaf(di, p.x, b0.z); f[3] = fmaf(di, p.y, b0.w);
        p = __half22float2(a[2]); f[4] = fmaf(di, p.x, b1.x); f[5] = fmaf(di, p.y, b1.y);
        p = __half22float2(a[3]); f[6] = fmaf(di, p.x, b1.z); f[7] = fmaf(di, p.y, b1.w);
        float m = f[0];
        #pragma unroll
        for (int t = 1; t < 8; ++t) m = fmaxf(m, f[t]);
        m = fmaxf(m, __shfl_xor(m, 1));              // partners stay within lanes 0..7
        m = fmaxf(m, __shfl_xor(m, 2));
        m = fmaxf(m, __shfl_xor(m, 4));
        float se = 0.f;
        #pragma unroll
        for (int t = 0; t < 8; ++t) se += __expf(f[t] - m);
        se += __shfl_xor(se, 1);
        se += __shfl_xor(se, 2);
        se += __shfl_xor(se, 4);
        float ls = m + logf(se);
        float4 o0 = {f[0] - ls, f[1] - ls, f[2] - ls, f[3] - ls};
        float4 o1 = {f[4] - ls, f[5] - ls, f[6] - ls, f[7] - ls};
        float4* op = (float4*)(out + (size_t)i * NCLS);
        op[q * 2] = o0; op[q * 2 + 1] = o1;
    }
}

// ---------- launch ----------

static inline size_t align256(size_t v) { return (v + 255) & ~(size_t)255; }

extern "C" void kernel_launch(void* const* d_in, const int* in_sizes, int n_in,
                              void* d_out, int out_size, void* d_ws, size_t ws_size,
                              hipStream_t stream) {
    const float* x  = (const float*)d_in[0];
    const int*   ei = (const int*)d_in[1];
    const float* W  = (const float*)d_in[2];
    const float* b  = (const float*)d_in[3];
    float* out = (float*)d_out;

    const int N = in_sizes[0] / NFEAT;   // 50000
    const int E = in_sizes[1] / 2;       // 800000
    const int* src = ei;
    const int* dst = ei + E;
    const int NBUCK = (N + 255) >> 8;    // 196 buckets of 256 nodes

    const int CSR_CAP = E + BSLACK * NBUCK + 64;   // pads/self slack + overrun slack

    char* ws = (char*)d_ws;
    size_t o = 0;
    int*          h     = (int*)(ws + o);          o += align256((size_t)NBLK * NBUCK * 4);
    int*          btot  = (int*)(ws + o);          o += align256(256 * 4);
    unsigned int* bedg  = (unsigned int*)(ws + o); o += align256((size_t)E * 4);
    int*          csr   = (int*)(ws + o);          o += align256((size_t)CSR_CAP * 4);
    int*          rbeg  = (int*)(ws + o);          o += align256((size_t)N * 4);
    int*          rend  = (int*)(ws + o);          o += align256((size_t)N * 4);
    float*        dinv  = (float*)(ws + o);        o += align256((size_t)N * 4);
    __half*       zh    = (__half*)(ws + o);       o += align256((size_t)(N + 1) * NCLS * 2);
    __half*       y1h   = (__half*)(ws + o);       o += align256((size_t)(N + 1) * NCLS * 2);

    const int E4 = (E + 3) / 4;

    hist_kernel<<<NBLK, 256, 0, stream>>>(dst, h, E4, E, NBUCK);
    colscan_kernel<<<NBUCK, 256, 0, stream>>>(h, btot, NBUCK);
    bucket_scatter_kernel<<<NBLK, 256, 0, stream>>>(src, dst, h, btot, bedg, E4, E, NBUCK);
    drain_kernel<<<NBUCK, 256, 0, stream>>>(bedg, btot, csr, rbeg, rend, dinv, N, NBUCK);
    gemm_kernel<<<(N + 63) / 64, 512, 0, stream>>>(x, W, dinv, zh, y1h, N);
    hop64_kernel<1><<<(N + 3) / 4, 256, 0, stream>>>(zh, dinv, rbeg, rend, csr, y1h, N);
    hop2cls_kernel<<<(N + 3) / 4, 256, 0, stream>>>(y1h, dinv, rbeg, rend, csr, b, out, N);
}